// Round 3
// baseline (666.236 us; speedup 1.0000x reference)
//
#include <hip/hip_runtime.h>

typedef unsigned short u16;
typedef unsigned int u32;
typedef unsigned long long u64;

#define T_TOK 8192
#define DIM 768
#define FF 3072
#define NE 8
#define CAP 2560
#define LSTR 5120

typedef __attribute__((ext_vector_type(8))) short s8v;
typedef __attribute__((ext_vector_type(4))) float f4v;

__device__ __forceinline__ u16 f2bf(float f) {
  union { float f; u32 u; } v; v.f = f;
  u32 r = v.u + 0x7FFFu + ((v.u >> 16) & 1u);
  return (u16)(r >> 16);
}

__device__ __forceinline__ void glds16(const void* g, void* l) {
  __builtin_amdgcn_global_load_lds(
      (const __attribute__((address_space(1))) u32*)g,
      (__attribute__((address_space(3))) u32*)l, 16, 0, 0);
}

// raw barrier: convergent builtin + compiler memory fence; does NOT drain counters
#define BARRIER() do { asm volatile("" ::: "memory"); __builtin_amdgcn_s_barrier(); asm volatile("" ::: "memory"); } while (0)
#define WAITV(N) asm volatile("s_waitcnt vmcnt(" #N ")" ::: "memory")
#define WAITL() asm volatile("s_waitcnt lgkmcnt(0)" ::: "memory")
#define PRIO1 __builtin_amdgcn_s_setprio(1)
#define PRIO0 __builtin_amdgcn_s_setprio(0)

// ---------------- fused cast of the 3 weight tensors fp32 -> bf16 ----------------
__global__ __launch_bounds__(256) void cast3_kernel(
    const float* __restrict__ s0, const float* __restrict__ s1, const float* __restrict__ s2,
    u16* __restrict__ d0, u16* __restrict__ d1, u16* __restrict__ d2, int n8each) {
  int i = blockIdx.x * 256 + threadIdx.x;
  const float* s; u16* d; int j;
  if (i < n8each) { s = s0; d = d0; j = i; }
  else if (i < 2 * n8each) { s = s1; d = d1; j = i - n8each; }
  else { s = s2; d = d2; j = i - 2 * n8each; }
  const float4* s4 = (const float4*)s;
  float4 a = s4[2 * j], b = s4[2 * j + 1];
  uint4 o;
  o.x = (u32)f2bf(a.x) | ((u32)f2bf(a.y) << 16);
  o.y = (u32)f2bf(a.z) | ((u32)f2bf(a.w) << 16);
  o.z = (u32)f2bf(b.x) | ((u32)f2bf(b.y) << 16);
  o.w = (u32)f2bf(b.z) | ((u32)f2bf(b.w) << 16);
  ((uint4*)d)[j] = o;
}

// ---------------- router: one wave per token, NO atomics; also emits xb (bf16 x) ----------------
__global__ __launch_bounds__(256) void router_kernel(
    const float* __restrict__ x, const float* __restrict__ wg, u16* __restrict__ xb,
    int* __restrict__ tki, float* __restrict__ tkp,
    float* __restrict__ probs, float* __restrict__ lse2) {
  int lane = threadIdx.x & 63;
  int t = blockIdx.x * 4 + (threadIdx.x >> 6);
  const float* xr = x + (long)t * DIM;
  u16* xw = xb + (long)t * DIM;
  float acc[NE];
#pragma unroll
  for (int e = 0; e < NE; e++) acc[e] = 0.f;
  for (int i = 0; i < DIM / 64; i++) {
    float xv = xr[lane + 64 * i];
    xw[lane + 64 * i] = f2bf(xv);
#pragma unroll
    for (int e = 0; e < NE; e++) acc[e] += xv * wg[e * DIM + lane + 64 * i];
  }
#pragma unroll
  for (int off = 32; off > 0; off >>= 1) {
#pragma unroll
    for (int e = 0; e < NE; e++) acc[e] += __shfl_xor(acc[e], off);
  }
  if (lane == 0) {
    float m = acc[0];
#pragma unroll
    for (int e = 1; e < NE; e++) m = fmaxf(m, acc[e]);
    float p[NE], s = 0.f;
#pragma unroll
    for (int e = 0; e < NE; e++) { p[e] = __expf(acc[e] - m); s += p[e]; }
    float inv = 1.f / s;
    int e0 = 0;
#pragma unroll
    for (int e = 1; e < NE; e++) if (acc[e] > acc[e0]) e0 = e;
    int e1 = (e0 == 0) ? 1 : 0;
#pragma unroll
    for (int e = 0; e < NE; e++) if (e != e0 && acc[e] > acc[e1]) e1 = e;
    float p0 = p[e0] * inv, p1 = p[e1] * inv;
    float rn = 1.f / (p0 + p1);
    tki[2 * t] = e0; tki[2 * t + 1] = e1;
    tkp[2 * t] = p0 * rn; tkp[2 * t + 1] = p1 * rn;
    float4 pa = {p[0] * inv, p[1] * inv, p[2] * inv, p[3] * inv};
    float4 pb = {p[4] * inv, p[5] * inv, p[6] * inv, p[7] * inv};
    ((float4*)(probs + t * 8))[0] = pa;
    ((float4*)(probs + t * 8))[1] = pb;
    float lse = __logf(s) + m;
    lse2[t] = lse * lse;
  }
}

// ---------------- reduce router stats ----------------
__global__ __launch_bounds__(1024) void reduce_router_kernel(
    const int* __restrict__ tki, const float* __restrict__ probs, const float* __restrict__ lse2,
    int* __restrict__ fcnt, float* __restrict__ psum, float* __restrict__ zsum) {
  int t = blockIdx.x * 1024 + threadIdx.x;
  float4 pa = ((const float4*)(probs + t * 8))[0];
  float4 pb = ((const float4*)(probs + t * 8))[1];
  float p[8] = {pa.x, pa.y, pa.z, pa.w, pb.x, pb.y, pb.z, pb.w};
  float z = lse2[t];
  int e0 = tki[2 * t], e1 = tki[2 * t + 1];
  int fc[8];
#pragma unroll
  for (int e = 0; e < 8; e++) fc[e] = (e0 == e ? 1 : 0) + (e1 == e ? 1 : 0);
#pragma unroll
  for (int off = 32; off > 0; off >>= 1) {
#pragma unroll
    for (int e = 0; e < 8; e++) { p[e] += __shfl_xor(p[e], off); fc[e] += __shfl_xor(fc[e], off); }
    z += __shfl_xor(z, off);
  }
  __shared__ float sp[16][9];
  __shared__ int sf[16][8];
  int wv = threadIdx.x >> 6, lane = threadIdx.x & 63;
  if (lane == 0) {
#pragma unroll
    for (int e = 0; e < 8; e++) { sp[wv][e] = p[e]; sf[wv][e] = fc[e]; }
    sp[wv][8] = z;
  }
  __syncthreads();
  if (threadIdx.x < 9) {
    float s = 0.f;
    for (int w = 0; w < 16; w++) s += sp[w][threadIdx.x];
    if (threadIdx.x < 8) atomicAdd(&psum[threadIdx.x], s);
    else atomicAdd(zsum, s);
  }
  if (threadIdx.x >= 64 && threadIdx.x < 72) {
    int e = threadIdx.x - 64;
    int s = 0;
    for (int w = 0; w < 16; w++) s += sf[w][e];
    atomicAdd(&fcnt[e], s);
  }
}

// ---------------- rank + dispatch: deterministic positions, NO atomics ----------------
__global__ __launch_bounds__(1024) void rank_dispatch_kernel(
    const int* __restrict__ tki, const float* __restrict__ tkp,
    int* __restrict__ ltk, float* __restrict__ lw,
    int* __restrict__ counts, int* __restrict__ baserow, int* __restrict__ kflags) {
  __shared__ int wave_cnt[2][16][8];
  __shared__ int base[2][8];
  __shared__ int sc0[8];
  int tid = threadIdx.x, wv = tid >> 6, lane = tid & 63;
  int c0w[8];
#pragma unroll
  for (int e = 0; e < 8; e++) c0w[e] = 0;
  for (int c = 0; c < T_TOK / 1024; c++) {
    int e0 = tki[2 * (c * 1024 + tid)];
#pragma unroll
    for (int e = 0; e < 8; e++) {
      u64 m = __ballot(e0 == e);
      if (lane == 0) c0w[e] += __popcll(m);
    }
  }
  if (lane == 0) {
#pragma unroll
    for (int e = 0; e < 8; e++) wave_cnt[0][wv][e] = c0w[e];
  }
  if (tid < 16) base[tid >> 3][tid & 7] = 0;
  __syncthreads();
  if (tid < 8) {
    int s = 0;
    for (int w = 0; w < 16; w++) s += wave_cnt[0][w][tid];
    sc0[tid] = (s < CAP) ? s : CAP;
  }
  __syncthreads();
  u64 lmask = (lane == 63) ? 0x7FFFFFFFFFFFFFFFull : ((1ull << lane) - 1ull);
  for (int c = 0; c < T_TOK / 1024; c++) {
    int t = c * 1024 + tid;
    int e0 = tki[2 * t], e1 = tki[2 * t + 1];
    float p0 = tkp[2 * t], p1 = tkp[2 * t + 1];
    int pre0 = 0, pre1 = 0;
    for (int e = 0; e < 8; e++) {
      u64 m0 = __ballot(e0 == e);
      if (e0 == e) pre0 = __popcll(m0 & lmask);
      if (lane == 0) wave_cnt[0][wv][e] = __popcll(m0);
      u64 m1 = __ballot(e1 == e);
      if (e1 == e) pre1 = __popcll(m1 & lmask);
      if (lane == 0) wave_cnt[1][wv][e] = __popcll(m1);
    }
    __syncthreads();
    if (tid < 16) {
      int k = tid >> 3, e = tid & 7;
      int run = base[k][e];
      for (int w = 0; w < 16; w++) {
        int v = wave_cnt[k][w][e];
        wave_cnt[k][w][e] = run;
        run += v;
      }
      base[k][e] = run;
    }
    __syncthreads();
    int r0 = wave_cnt[0][wv][e0] + pre0;
    int r1 = wave_cnt[1][wv][e1] + pre1;
    if (r0 < CAP) { ltk[e0 * LSTR + r0] = (t << 1); lw[e0 * LSTR + r0] = p0; }
    if (r1 < CAP) {
      int p = sc0[e1] + r1;
      ltk[e1 * LSTR + p] = (t << 1) | 1; lw[e1 * LSTR + p] = p1;
    }
    kflags[t] = (r0 < CAP ? 1 : 0) | (r1 < CAP ? 2 : 0);
    __syncthreads();
  }
  if (tid == 0) {
    int run = 0;
    for (int e = 0; e < 8; e++) {
      int c1 = base[1][e]; if (c1 > CAP) c1 = CAP;
      int cnt = sc0[e] + c1;
      counts[e] = cnt; baserow[e] = run; run += cnt;
    }
  }
}

// ================= 8-phase 256x256 GEMM kernels =================
// Fragment load macros (XOR-swizzled LDS reads, BK=64 => kk slots quad / quad+4)
#define LOADA(MS, PB) \
  _Pragma("unroll") for (int i_ = 0; i_ < 4; i_++) { \
    const u16* rp_ = (PB) + ((MS) * 64 + i_ * 16 + lrow) * 64; \
    a[i_][0] = *(const s8v*)(rp_ + sx0); \
    a[i_][1] = *(const s8v*)(rp_ + sx1); }
#define LOADB(DST, NS, PB) \
  _Pragma("unroll") for (int j_ = 0; j_ < 2; j_++) { \
    const u16* rp_ = (PB) + (cb + (NS) * 32 + j_ * 16 + lrow) * 64; \
    DST[j_][0] = *(const s8v*)(rp_ + sx0); \
    DST[j_][1] = *(const s8v*)(rp_ + sx1); }
#define QMFMA(MS, NS, BREG) \
  _Pragma("unroll") for (int i_ = 0; i_ < 4; i_++) { \
    _Pragma("unroll") for (int j_ = 0; j_ < 2; j_++) { \
      acc[(MS) * 4 + i_][(NS) * 2 + j_] = __builtin_amdgcn_mfma_f32_16x16x32_bf16( \
          a[i_][0], BREG[j_][0], acc[(MS) * 4 + i_][(NS) * 2 + j_], 0, 0, 0); \
      acc[(MS) * 4 + i_][(NS) * 2 + j_] = __builtin_amdgcn_mfma_f32_16x16x32_bf16( \
          a[i_][1], BREG[j_][1], acc[(MS) * 4 + i_][(NS) * 2 + j_], 0, 0, 0); } }

// ---------------- GEMM1: H = silu(x@Wg^T) * (x@Wu^T) ----------------
// BM=256 tokens, Wcat-N=256 (=128 H cols, gate/up interleaved by 16 rows), BK=64, NK=12
__global__ __launch_bounds__(512, 2) void gemm1_kernel(
    const u16* __restrict__ xb, const u16* __restrict__ wgb, const u16* __restrict__ wub,
    u16* __restrict__ H, const int* __restrict__ counts, const int* __restrict__ baserow,
    const int* __restrict__ ltk) {
  // grid 1920 = 8 XCD chunks x 240; within chunk: e/NT contiguous, mt fastest
  int id = blockIdx.x;
  int wgi = (id & 7) * 240 + (id >> 3);
  int e = wgi / 240;
  int rem = wgi - e * 240;
  int NT = rem / 10;          // [0,24) Wcat 256-col tile
  int mt = rem - NT * 10;     // [0,10)
  int cnt = counts[e];
  if (mt * 256 >= cnt) return;

  __shared__ u16 A[2][2][128 * 64];
  __shared__ u16 B[2][2][128 * 64];
  __shared__ int toks[256];
  int tid = threadIdx.x;
  if (tid < 256) {
    int r = mt * 256 + tid; if (r > cnt - 1) r = cnt - 1;
    toks[tid] = ltk[e * LSTR + r] >> 1;
  }
  __syncthreads();

#define STAGE_A1(P, H_, KT) do { \
    int S_ = tid; \
    _Pragma("unroll") for (int c_ = 0; c_ < 2; c_++, S_ += 512) { \
      int row_ = S_ >> 3; int l_ = (S_ & 7) ^ (row_ & 7); \
      glds16(xb + (long)toks[(H_) * 128 + row_] * DIM + (KT) * 64 + l_ * 8, \
             &A[P][H_][S_ * 8]); \
    } } while (0)
#define STAGE_B1(P, H_, KT) do { \
    int S_ = tid; \
    _Pragma("unroll") for (int c_ = 0; c_ < 2; c_++, S_ += 512) { \
      int row_ = S_ >> 3; int l_ = (S_ & 7) ^ (row_ & 7); \
      int rr_ = NT * 256 + (H_) * 128 + row_; \
      int f_ = ((rr_ >> 5) << 4) + (rr_ & 15); \
      const u16* bs_ = ((rr_ >> 4) & 1) ? wub : wgb; \
      glds16(bs_ + ((long)e * FF + f_) * DIM + (KT) * 64 + l_ * 8, \
             &B[P][H_][S_ * 8]); \
    } } while (0)

  int lane = tid & 63, wv = tid >> 6;
  int wm = (wv & 1) * 128;    // wave A-half
  int wn = (wv >> 1) * 64;    // wave B 64-col range
  int lrow = lane & 15, quad = lane >> 4;
  int cb = wn & 64;
  int sx0 = (quad ^ (lrow & 7)) * 8;
  int sx1 = ((quad + 4) ^ (lrow & 7)) * 8;
  const u16* Awb = &A[0][wm >> 7][0];
  const u16* Bwb = &B[0][wn >> 7][0];

  f4v acc[8][4];
#pragma unroll
  for (int i = 0; i < 8; i++)
#pragma unroll
    for (int j = 0; j < 4; j++) acc[i][j] = (f4v){0.f, 0.f, 0.f, 0.f};
  s8v a[4][2], b0[2][2], b1[2][2];

  // prologue: tile0 all 4 halves, tile1 B-lo + A-lo
  STAGE_A1(0, 0, 0); STAGE_A1(0, 1, 0); STAGE_B1(0, 0, 0); STAGE_B1(0, 1, 0);
  STAGE_B1(1, 0, 1); STAGE_A1(1, 0, 1);
  WAITV(4);
  BARRIER();

  for (int kt = 0; kt < 12; kt++) {
    int p = kt & 1;
    const u16* Ap = Awb + p * (2 * 128 * 64);
    const u16* Bp = Bwb + p * (2 * 128 * 64);
    // q0: reads A-m0,B-n0; stage A-hi(kt+1)
    LOADA(0, Ap);
    LOADB(b0, 0, Bp);
    if (kt + 1 < 12) STAGE_A1(p ^ 1, 1, kt + 1);
    BARRIER(); WAITL();
    PRIO1; QMFMA(0, 0, b0); PRIO0;
    BARRIER();
    // q1: reads B-n1; stage B-hi(kt+1)
    LOADB(b1, 1, Bp);
    if (kt + 1 < 12) STAGE_B1(p ^ 1, 1, kt + 1);
    BARRIER(); WAITL();
    PRIO1; QMFMA(0, 1, b1); PRIO0;
    BARRIER();
    // q2: reads A-m1; stage B-lo(kt+2)
    LOADA(1, Ap);
    if (kt + 2 < 12) STAGE_B1(p, 0, kt + 2);
    BARRIER(); WAITL();
    PRIO1; QMFMA(1, 1, b1); PRIO0;
    BARRIER();
    // q3: stage A-lo(kt+2); counted wait (drain only in last 2 iters)
    if (kt + 2 < 12) STAGE_A1(p, 0, kt + 2);
    if (kt < 10) { WAITV(4); } else { WAITV(0); }
    BARRIER();
    PRIO1; QMFMA(1, 0, b0); PRIO0;
    BARRIER();
  }

  long hb = (long)baserow[e] + (long)mt * 256;
#pragma unroll
  for (int mi = 0; mi < 8; mi++) {
#pragma unroll
    for (int r4 = 0; r4 < 4; r4++) {
      int m = wm + (mi >> 2) * 64 + (mi & 3) * 16 + quad * 4 + r4;
      if (mt * 256 + m < cnt) {
#pragma unroll
        for (int pr = 0; pr < 2; pr++) {
          float gv = acc[mi][pr * 2][r4], uv = acc[mi][pr * 2 + 1][r4];
          float h = gv / (1.f + __expf(-gv)) * uv;
          H[(hb + m) * FF + NT * 128 + (wn >> 1) + pr * 16 + lrow] = f2bf(h);
        }
      }
    }
  }
#undef STAGE_A1
#undef STAGE_B1
}

// ---------------- GEMM2: ybuf[(t,k)] = (H @ wo^T) * w ----------------
// BM=256 H rows, BN=256 DIM cols (nt in {0,1,2}), BK=64, NK=48
__global__ __launch_bounds__(512, 2) void gemm2_kernel(
    const u16* __restrict__ Hsrc, const u16* __restrict__ wob,
    float* __restrict__ ybuf, const int* __restrict__ counts, const int* __restrict__ baserow,
    const int* __restrict__ ltk, const float* __restrict__ lw) {
  // grid 240 = 8 XCD chunks x 30; within chunk: e fixed-ish, mt/nt contiguous
  int id = blockIdx.x;
  int wgi = (id & 7) * 30 + (id >> 3);
  int e = wgi / 30;
  int rem = wgi - e * 30;
  int mt = rem / 3;
  int nt = rem - mt * 3;
  int cnt = counts[e];
  if (mt * 256 >= cnt) return;

  __shared__ u16 A[2][2][128 * 64];
  __shared__ u16 B[2][2][128 * 64];
  __shared__ int stok[256];
  __shared__ float sw[256];
  int tid = threadIdx.x;
  if (tid < 256) {
    int r = mt * 256 + tid; if (r > cnt - 1) r = cnt - 1;
    stok[tid] = ltk[e * LSTR + r];
    sw[tid] = lw[e * LSTR + r];
  }
  __syncthreads();
  long hb0 = baserow[e];

#define STAGE_A2(P, H_, KT) do { \
    int S_ = tid; \
    _Pragma("unroll") for (int c_ = 0; c_ < 2; c_++, S_ += 512) { \
      int row_ = S_ >> 3; int l_ = (S_ & 7) ^ (row_ & 7); \
      int r_ = mt * 256 + (H_) * 128 + row_; if (r_ > cnt - 1) r_ = cnt - 1; \
      glds16(Hsrc + (hb0 + r_) * FF + (KT) * 64 + l_ * 8, &A[P][H_][S_ * 8]); \
    } } while (0)
#define STAGE_B2(P, H_, KT) do { \
    int S_ = tid; \
    _Pragma("unroll") for (int c_ = 0; c_ < 2; c_++, S_ += 512) { \
      int row_ = S_ >> 3; int l_ = (S_ & 7) ^ (row_ & 7); \
      glds16(wob + ((long)e * DIM + nt * 256 + (H_) * 128 + row_) * FF + (KT) * 64 + l_ * 8, \
             &B[P][H_][S_ * 8]); \
    } } while (0)

  int lane = tid & 63, wv = tid >> 6;
  int wm = (wv & 1) * 128;
  int wn = (wv >> 1) * 64;
  int lrow = lane & 15, quad = lane >> 4;
  int cb = wn & 64;
  int sx0 = (quad ^ (lrow & 7)) * 8;
  int sx1 = ((quad + 4) ^ (lrow & 7)) * 8;
  const u16* Awb = &A[0][wm >> 7][0];
  const u16* Bwb = &B[0][wn >> 7][0];

  f4v acc[8][4];
#pragma unroll
  for (int i = 0; i < 8; i++)
#pragma unroll
    for (int j = 0; j < 4; j++) acc[i][j] = (f4v){0.f, 0.f, 0.f, 0.f};
  s8v a[4][2], b0[2][2], b1[2][2];

  STAGE_A2(0, 0, 0); STAGE_A2(0, 1, 0); STAGE_B2(0, 0, 0); STAGE_B2(0, 1, 0);
  STAGE_B2(1, 0, 1); STAGE_A2(1, 0, 1);
  WAITV(4);
  BARRIER();

  for (int kt = 0; kt < 48; kt++) {
    int p = kt & 1;
    const u16* Ap = Awb + p * (2 * 128 * 64);
    const u16* Bp = Bwb + p * (2 * 128 * 64);
    LOADA(0, Ap);
    LOADB(b0, 0, Bp);
    if (kt + 1 < 48) STAGE_A2(p ^ 1, 1, kt + 1);
    BARRIER(); WAITL();
    PRIO1; QMFMA(0, 0, b0); PRIO0;
    BARRIER();
    LOADB(b1, 1, Bp);
    if (kt + 1 < 48) STAGE_B2(p ^ 1, 1, kt + 1);
    BARRIER(); WAITL();
    PRIO1; QMFMA(0, 1, b1); PRIO0;
    BARRIER();
    LOADA(1, Ap);
    if (kt + 2 < 48) STAGE_B2(p, 0, kt + 2);
    BARRIER(); WAITL();
    PRIO1; QMFMA(1, 1, b1); PRIO0;
    BARRIER();
    if (kt + 2 < 48) STAGE_A2(p, 0, kt + 2);
    if (kt < 46) { WAITV(4); } else { WAITV(0); }
    BARRIER();
    PRIO1; QMFMA(1, 0, b0); PRIO0;
    BARRIER();
  }

#pragma unroll
  for (int mi = 0; mi < 8; mi++) {
#pragma unroll
    for (int r4 = 0; r4 < 4; r4++) {
      int m = wm + (mi >> 2) * 64 + (mi & 3) * 16 + quad * 4 + r4;
      if (mt * 256 + m < cnt) {
        int entry = stok[m];
        float w = sw[m];
        long ob = (long)entry * DIM + nt * 256 + wn;
#pragma unroll
        for (int jc = 0; jc < 4; jc++)
          ybuf[ob + jc * 16 + lrow] = acc[mi][jc][r4] * w;
      }
    }
  }
#undef STAGE_A2
#undef STAGE_B2
}

// ---------------- combine: out[t] = sum of kept (t,k) contributions ----------------
__global__ __launch_bounds__(256) void combine_kernel(
    const float* __restrict__ ybuf, const int* __restrict__ kflags, float* __restrict__ out) {
  int idx = blockIdx.x * 256 + threadIdx.x;   // [0, T*DIM/4)
  int t = idx / (DIM / 4);
  int d4 = idx - t * (DIM / 4);
  int kf = kflags[t];
  float4 r = {0.f, 0.f, 0.f, 0.f};
  if (kf & 1) {
    float4 a = ((const float4*)(ybuf + (long)(2 * t) * DIM))[d4];
    r.x += a.x; r.y += a.y; r.z += a.z; r.w += a.w;
  }
  if (kf & 2) {
    float4 b = ((const float4*)(ybuf + (long)(2 * t + 1) * DIM))[d4];
    r.x += b.x; r.y += b.y; r.z += b.z; r.w += b.w;
  }
  ((float4*)out)[idx] = r;
}

// ---------------- aux loss ----------------
__global__ void aux_kernel(const int* __restrict__ fcnt, const float* __restrict__ psum,
                           const float* __restrict__ zsum, float* __restrict__ outaux) {
  if (threadIdx.x == 0 && blockIdx.x == 0) {
    float lb = 0.f;
    for (int e = 0; e < 8; e++)
      lb += ((float)fcnt[e] / (float)(T_TOK * 2)) * (psum[e] / (float)T_TOK);
    lb *= 8.f;
    float z = zsum[0] / (float)T_TOK;
    outaux[0] = 0.01f * lb + 0.001f * z;
  }
}

extern "C" void kernel_launch(void* const* d_in, const int* in_sizes, int n_in,
                              void* d_out, int out_size, void* d_ws, size_t ws_size,
                              hipStream_t stream) {
  const float* x = (const float*)d_in[0];
  const float* wgate = (const float*)d_in[1];
  const float* wig = (const float*)d_in[2];
  const float* wiu = (const float*)d_in[3];
  const float* wo = (const float*)d_in[4];
  float* out = (float*)d_out;

  char* ws = (char*)d_ws;
  size_t off = 0;
  auto alloc = [&](size_t bytes) {
    void* p = ws + off;
    off += (bytes + 255) & ~(size_t)255;
    return p;
  };
  int* ctrl = (int*)alloc(256);
  u16* xb = (u16*)alloc((size_t)T_TOK * DIM * 2);
  u16* wgb = (u16*)alloc((size_t)NE * FF * DIM * 2);
  u16* wub = (u16*)alloc((size_t)NE * FF * DIM * 2);
  u16* wob = (u16*)alloc((size_t)NE * DIM * FF * 2);
  u16* Hbuf = (u16*)alloc((size_t)(T_TOK * 2 + 256) * FF * 2);
  int* tki = (int*)alloc((size_t)T_TOK * 2 * 4);
  float* tkp = (float*)alloc((size_t)T_TOK * 2 * 4);
  int* ltk = (int*)alloc((size_t)NE * LSTR * 4);
  float* lw = (float*)alloc((size_t)NE * LSTR * 4);
  float* probs = (float*)alloc((size_t)T_TOK * 8 * 4);
  float* lse2 = (float*)alloc((size_t)T_TOK * 4);
  int* kflags = (int*)alloc((size_t)T_TOK * 4);
  // ybuf [T*2, DIM] fp32 (50.3MB) aliases wgb+wub (75.5MB): weights dead after gemm1
  float* ybuf = (float*)wgb;

  int* fcnt = ctrl;
  int* counts = ctrl + 8;
  int* baserow = ctrl + 16;
  float* psum = (float*)(ctrl + 24);
  float* zsum = (float*)(ctrl + 32);

  const int n8each = NE * FF * DIM / 8;
  hipMemsetAsync(ctrl, 0, 256, stream);
  cast3_kernel<<<3 * n8each / 256, 256, 0, stream>>>(wig, wiu, wo, wgb, wub, wob, n8each);
  router_kernel<<<T_TOK / 4, 256, 0, stream>>>(x, wgate, xb, tki, tkp, probs, lse2);
  reduce_router_kernel<<<T_TOK / 1024, 1024, 0, stream>>>(tki, probs, lse2, fcnt, psum, zsum);
  rank_dispatch_kernel<<<1, 1024, 0, stream>>>(tki, tkp, ltk, lw, counts, baserow, kflags);
  gemm1_kernel<<<1920, 512, 0, stream>>>(xb, wgb, wub, Hbuf, counts, baserow, ltk);
  gemm2_kernel<<<240, 512, 0, stream>>>(Hbuf, wob, ybuf, counts, baserow, ltk, lw);
  combine_kernel<<<T_TOK * DIM / 4 / 256, 256, 0, stream>>>(ybuf, kflags, out);
  aux_kernel<<<1, 64, 0, stream>>>(fcnt, psum, zsum, out + (size_t)T_TOK * DIM);
}

// Round 4
// 616.180 us; speedup vs baseline: 1.0812x; 1.0812x over previous
//
#include <hip/hip_runtime.h>

typedef unsigned short u16;
typedef unsigned int u32;
typedef unsigned long long u64;

#define T_TOK 8192
#define DIM 768
#define FF 3072
#define NE 8
#define CAP 2560
#define LSTR 5120

typedef __attribute__((ext_vector_type(8))) short s8v;
typedef __attribute__((ext_vector_type(4))) float f4v;

__device__ __forceinline__ u16 f2bf(float f) {
  union { float f; u32 u; } v; v.f = f;
  u32 r = v.u + 0x7FFFu + ((v.u >> 16) & 1u);
  return (u16)(r >> 16);
}

__device__ __forceinline__ void glds16(const void* g, void* l) {
  __builtin_amdgcn_global_load_lds(
      (const __attribute__((address_space(1))) u32*)g,
      (__attribute__((address_space(3))) u32*)l, 16, 0, 0);
}

// raw barrier: convergent builtin + compiler memory fence; does NOT drain counters
#define BARRIER() do { asm volatile("" ::: "memory"); __builtin_amdgcn_s_barrier(); asm volatile("" ::: "memory"); } while (0)
#define WAITV(N) asm volatile("s_waitcnt vmcnt(" #N ")" ::: "memory")
#define WAITL() asm volatile("s_waitcnt lgkmcnt(0)" ::: "memory")
#define PRIO1 __builtin_amdgcn_s_setprio(1)
#define PRIO0 __builtin_amdgcn_s_setprio(0)

// ---------------- fused cast of the 3 weight tensors fp32 -> bf16 ----------------
__global__ __launch_bounds__(256) void cast3_kernel(
    const float* __restrict__ s0, const float* __restrict__ s1, const float* __restrict__ s2,
    u16* __restrict__ d0, u16* __restrict__ d1, u16* __restrict__ d2, int n8each) {
  int i = blockIdx.x * 256 + threadIdx.x;
  const float* s; u16* d; int j;
  if (i < n8each) { s = s0; d = d0; j = i; }
  else if (i < 2 * n8each) { s = s1; d = d1; j = i - n8each; }
  else { s = s2; d = d2; j = i - 2 * n8each; }
  const float4* s4 = (const float4*)s;
  float4 a = s4[2 * j], b = s4[2 * j + 1];
  uint4 o;
  o.x = (u32)f2bf(a.x) | ((u32)f2bf(a.y) << 16);
  o.y = (u32)f2bf(a.z) | ((u32)f2bf(a.w) << 16);
  o.z = (u32)f2bf(b.x) | ((u32)f2bf(b.y) << 16);
  o.w = (u32)f2bf(b.z) | ((u32)f2bf(b.w) << 16);
  ((uint4*)d)[j] = o;
}

// ---------------- router: one wave per token, NO atomics; also emits xb (bf16 x) ----------------
__global__ __launch_bounds__(256) void router_kernel(
    const float* __restrict__ x, const float* __restrict__ wg, u16* __restrict__ xb,
    int* __restrict__ tki, float* __restrict__ tkp,
    float* __restrict__ probs, float* __restrict__ lse2) {
  int lane = threadIdx.x & 63;
  int t = blockIdx.x * 4 + (threadIdx.x >> 6);
  const float* xr = x + (long)t * DIM;
  u16* xw = xb + (long)t * DIM;
  float acc[NE];
#pragma unroll
  for (int e = 0; e < NE; e++) acc[e] = 0.f;
  for (int i = 0; i < DIM / 64; i++) {
    float xv = xr[lane + 64 * i];
    xw[lane + 64 * i] = f2bf(xv);
#pragma unroll
    for (int e = 0; e < NE; e++) acc[e] += xv * wg[e * DIM + lane + 64 * i];
  }
#pragma unroll
  for (int off = 32; off > 0; off >>= 1) {
#pragma unroll
    for (int e = 0; e < NE; e++) acc[e] += __shfl_xor(acc[e], off);
  }
  if (lane == 0) {
    float m = acc[0];
#pragma unroll
    for (int e = 1; e < NE; e++) m = fmaxf(m, acc[e]);
    float p[NE], s = 0.f;
#pragma unroll
    for (int e = 0; e < NE; e++) { p[e] = __expf(acc[e] - m); s += p[e]; }
    float inv = 1.f / s;
    int e0 = 0;
#pragma unroll
    for (int e = 1; e < NE; e++) if (acc[e] > acc[e0]) e0 = e;
    int e1 = (e0 == 0) ? 1 : 0;
#pragma unroll
    for (int e = 0; e < NE; e++) if (e != e0 && acc[e] > acc[e1]) e1 = e;
    float p0 = p[e0] * inv, p1 = p[e1] * inv;
    float rn = 1.f / (p0 + p1);
    tki[2 * t] = e0; tki[2 * t + 1] = e1;
    tkp[2 * t] = p0 * rn; tkp[2 * t + 1] = p1 * rn;
    float4 pa = {p[0] * inv, p[1] * inv, p[2] * inv, p[3] * inv};
    float4 pb = {p[4] * inv, p[5] * inv, p[6] * inv, p[7] * inv};
    ((float4*)(probs + t * 8))[0] = pa;
    ((float4*)(probs + t * 8))[1] = pb;
    float lse = __logf(s) + m;
    lse2[t] = lse * lse;
  }
}

// ---------------- reduce router stats ----------------
__global__ __launch_bounds__(1024) void reduce_router_kernel(
    const int* __restrict__ tki, const float* __restrict__ probs, const float* __restrict__ lse2,
    int* __restrict__ fcnt, float* __restrict__ psum, float* __restrict__ zsum) {
  int t = blockIdx.x * 1024 + threadIdx.x;
  float4 pa = ((const float4*)(probs + t * 8))[0];
  float4 pb = ((const float4*)(probs + t * 8))[1];
  float p[8] = {pa.x, pa.y, pa.z, pa.w, pb.x, pb.y, pb.z, pb.w};
  float z = lse2[t];
  int e0 = tki[2 * t], e1 = tki[2 * t + 1];
  int fc[8];
#pragma unroll
  for (int e = 0; e < 8; e++) fc[e] = (e0 == e ? 1 : 0) + (e1 == e ? 1 : 0);
#pragma unroll
  for (int off = 32; off > 0; off >>= 1) {
#pragma unroll
    for (int e = 0; e < 8; e++) { p[e] += __shfl_xor(p[e], off); fc[e] += __shfl_xor(fc[e], off); }
    z += __shfl_xor(z, off);
  }
  __shared__ float sp[16][9];
  __shared__ int sf[16][8];
  int wv = threadIdx.x >> 6, lane = threadIdx.x & 63;
  if (lane == 0) {
#pragma unroll
    for (int e = 0; e < 8; e++) { sp[wv][e] = p[e]; sf[wv][e] = fc[e]; }
    sp[wv][8] = z;
  }
  __syncthreads();
  if (threadIdx.x < 9) {
    float s = 0.f;
    for (int w = 0; w < 16; w++) s += sp[w][threadIdx.x];
    if (threadIdx.x < 8) atomicAdd(&psum[threadIdx.x], s);
    else atomicAdd(zsum, s);
  }
  if (threadIdx.x >= 64 && threadIdx.x < 72) {
    int e = threadIdx.x - 64;
    int s = 0;
    for (int w = 0; w < 16; w++) s += sf[w][e];
    atomicAdd(&fcnt[e], s);
  }
}

// ---------------- rank + dispatch: deterministic positions, NO atomics ----------------
__global__ __launch_bounds__(1024) void rank_dispatch_kernel(
    const int* __restrict__ tki, const float* __restrict__ tkp,
    int* __restrict__ ltk, float* __restrict__ lw,
    int* __restrict__ counts, int* __restrict__ baserow, int* __restrict__ kflags) {
  __shared__ int wave_cnt[2][16][8];
  __shared__ int base[2][8];
  __shared__ int sc0[8];
  int tid = threadIdx.x, wv = tid >> 6, lane = tid & 63;
  int c0w[8];
#pragma unroll
  for (int e = 0; e < 8; e++) c0w[e] = 0;
  for (int c = 0; c < T_TOK / 1024; c++) {
    int e0 = tki[2 * (c * 1024 + tid)];
#pragma unroll
    for (int e = 0; e < 8; e++) {
      u64 m = __ballot(e0 == e);
      if (lane == 0) c0w[e] += __popcll(m);
    }
  }
  if (lane == 0) {
#pragma unroll
    for (int e = 0; e < 8; e++) wave_cnt[0][wv][e] = c0w[e];
  }
  if (tid < 16) base[tid >> 3][tid & 7] = 0;
  __syncthreads();
  if (tid < 8) {
    int s = 0;
    for (int w = 0; w < 16; w++) s += wave_cnt[0][w][tid];
    sc0[tid] = (s < CAP) ? s : CAP;
  }
  __syncthreads();
  u64 lmask = (lane == 63) ? 0x7FFFFFFFFFFFFFFFull : ((1ull << lane) - 1ull);
  for (int c = 0; c < T_TOK / 1024; c++) {
    int t = c * 1024 + tid;
    int e0 = tki[2 * t], e1 = tki[2 * t + 1];
    float p0 = tkp[2 * t], p1 = tkp[2 * t + 1];
    int pre0 = 0, pre1 = 0;
    for (int e = 0; e < 8; e++) {
      u64 m0 = __ballot(e0 == e);
      if (e0 == e) pre0 = __popcll(m0 & lmask);
      if (lane == 0) wave_cnt[0][wv][e] = __popcll(m0);
      u64 m1 = __ballot(e1 == e);
      if (e1 == e) pre1 = __popcll(m1 & lmask);
      if (lane == 0) wave_cnt[1][wv][e] = __popcll(m1);
    }
    __syncthreads();
    if (tid < 16) {
      int k = tid >> 3, e = tid & 7;
      int run = base[k][e];
      for (int w = 0; w < 16; w++) {
        int v = wave_cnt[k][w][e];
        wave_cnt[k][w][e] = run;
        run += v;
      }
      base[k][e] = run;
    }
    __syncthreads();
    int r0 = wave_cnt[0][wv][e0] + pre0;
    int r1 = wave_cnt[1][wv][e1] + pre1;
    if (r0 < CAP) { ltk[e0 * LSTR + r0] = (t << 1); lw[e0 * LSTR + r0] = p0; }
    if (r1 < CAP) {
      int p = sc0[e1] + r1;
      ltk[e1 * LSTR + p] = (t << 1) | 1; lw[e1 * LSTR + p] = p1;
    }
    kflags[t] = (r0 < CAP ? 1 : 0) | (r1 < CAP ? 2 : 0);
    __syncthreads();
  }
  if (tid == 0) {
    int run = 0;
    for (int e = 0; e < 8; e++) {
      int c1 = base[1][e]; if (c1 > CAP) c1 = CAP;
      int cnt = sc0[e] + c1;
      counts[e] = cnt; baserow[e] = run; run += cnt;
    }
  }
}

// ================= 8-phase 256x256 GEMM kernels =================
// Fragment load macros (XOR-swizzled LDS reads, BK=64 => kk slots quad / quad+4)
#define LOADA(MS, PB) \
  _Pragma("unroll") for (int i_ = 0; i_ < 4; i_++) { \
    const u16* rp_ = (PB) + ((MS) * 64 + i_ * 16 + lrow) * 64; \
    a[i_][0] = *(const s8v*)(rp_ + sx0); \
    a[i_][1] = *(const s8v*)(rp_ + sx1); }
#define LOADB(DST, NS, PB) \
  _Pragma("unroll") for (int j_ = 0; j_ < 2; j_++) { \
    const u16* rp_ = (PB) + (cb + (NS) * 32 + j_ * 16 + lrow) * 64; \
    DST[j_][0] = *(const s8v*)(rp_ + sx0); \
    DST[j_][1] = *(const s8v*)(rp_ + sx1); }
#define QMFMA(MS, NS, BREG) \
  _Pragma("unroll") for (int i_ = 0; i_ < 4; i_++) { \
    _Pragma("unroll") for (int j_ = 0; j_ < 2; j_++) { \
      acc[(MS) * 4 + i_][(NS) * 2 + j_] = __builtin_amdgcn_mfma_f32_16x16x32_bf16( \
          a[i_][0], BREG[j_][0], acc[(MS) * 4 + i_][(NS) * 2 + j_], 0, 0, 0); \
      acc[(MS) * 4 + i_][(NS) * 2 + j_] = __builtin_amdgcn_mfma_f32_16x16x32_bf16( \
          a[i_][1], BREG[j_][1], acc[(MS) * 4 + i_][(NS) * 2 + j_], 0, 0, 0); } }

// Staging: all addresses precomputed in prologue (u32 element offsets vs kernel-arg
// bases; LDS dest = base + compile-time const + t8). Stage = 2 glds16, ~2 VALU.
#define STAGE_A(P, H, KT) do { \
    glds16(gAbase + (offA[H][0] + (u32)((KT) * 64)), aLds + ((P) * 2 + (H)) * 8192 + t8); \
    glds16(gAbase + (offA[H][1] + (u32)((KT) * 64)), aLds + ((P) * 2 + (H)) * 8192 + 4096 + t8); \
  } while (0)
#define STAGE_B(P, H, KT) do { \
    glds16(gBbase + (offB[H][0] + (u32)((KT) * 64)), bLds + ((P) * 2 + (H)) * 8192 + t8); \
    glds16(gBbase + (offB[H][1] + (u32)((KT) * 64)), bLds + ((P) * 2 + (H)) * 8192 + 4096 + t8); \
  } while (0)

// One K-tile, 4 quadrant phases; P is compile-time (loop unrolled by 2).
#define KTILE(KT, P, NK, WVN) do { \
    const u16* Ap = Awb + (P) * 16384; \
    const u16* Bp = Bwb + (P) * 16384; \
    LOADA(0, Ap); \
    LOADB(b0, 0, Bp); \
    if ((KT) + 1 < (NK)) STAGE_A((P) ^ 1, 1, (KT) + 1); \
    BARRIER(); WAITL(); \
    PRIO1; QMFMA(0, 0, b0); PRIO0; \
    BARRIER(); \
    LOADB(b1, 1, Bp); \
    if ((KT) + 1 < (NK)) STAGE_B((P) ^ 1, 1, (KT) + 1); \
    BARRIER(); WAITL(); \
    PRIO1; QMFMA(0, 1, b1); PRIO0; \
    BARRIER(); \
    LOADA(1, Ap); \
    if ((KT) + 2 < (NK)) STAGE_B(P, 0, (KT) + 2); \
    BARRIER(); WAITL(); \
    PRIO1; QMFMA(1, 1, b1); PRIO0; \
    BARRIER(); \
    if ((KT) + 2 < (NK)) STAGE_A(P, 0, (KT) + 2); \
    if ((KT) < (NK) - 2) { WAITV(4); } else { WAITV(0); } \
    BARRIER(); \
    PRIO1; QMFMA(1, 0, b0); PRIO0; \
    BARRIER(); \
  } while (0)

// ---------------- GEMM1: H = silu(x@Wg^T) * (x@Wu^T) ----------------
// BM=256 tokens, Wcat-N=256 (=128 H cols, gate/up interleaved by 16 rows), BK=64, NK=12
__global__ __launch_bounds__(512, 2) void gemm1_kernel(
    const u16* __restrict__ xb, const u16* __restrict__ wgb, const u16* __restrict__ wub,
    u16* __restrict__ H, const int* __restrict__ counts, const int* __restrict__ baserow,
    const int* __restrict__ ltk) {
  int id = blockIdx.x;
  int wgi = (id & 7) * 240 + (id >> 3);
  int e = wgi / 240;
  int rem = wgi - e * 240;
  int NT = rem / 10;          // [0,24) Wcat 256-col tile
  int mt = rem - NT * 10;     // [0,10)
  int cnt = counts[e];
  if (mt * 256 >= cnt) return;

  __shared__ u16 A[2][2][128 * 64];
  __shared__ u16 B[2][2][128 * 64];
  __shared__ int toks[256];
  int tid = threadIdx.x;
  if (tid < 256) {
    int r = mt * 256 + tid; if (r > cnt - 1) r = cnt - 1;
    toks[tid] = ltk[e * LSTR + r] >> 1;
  }
  __syncthreads();

  // ---- precompute staging offsets (u32 elements vs bases) ----
  const u16* gAbase = xb;
  const u16* gBbase = wgb;                 // wub = wgb + NE*FF*DIM in workspace
  u16* aLds = &A[0][0][0];
  u16* bLds = &B[0][0][0];
  int t8 = tid * 8;
  int row0 = tid >> 3, row1 = row0 + 64;   // chunk rows within a 128-row half
  int lsw = ((tid & 7) ^ (row0 & 7)) * 8;  // inverse-swizzled 16B slot (row1&7==row0&7)
  u32 offA[2][2], offB[2][2];
#pragma unroll
  for (int h = 0; h < 2; h++) {
    offA[h][0] = (u32)toks[h * 128 + row0] * DIM + lsw;
    offA[h][1] = (u32)toks[h * 128 + row1] * DIM + lsw;
#pragma unroll
    for (int c = 0; c < 2; c++) {
      int rowc = c ? row1 : row0;
      int rr = NT * 256 + h * 128 + rowc;           // Wcat row
      int f = ((rr >> 5) << 4) + (rr & 15);         // FF row within expert
      u32 o = (u32)(e * FF + f) * DIM + lsw;
      if ((rr >> 4) & 1) o += (u32)NE * FF * DIM;   // up-projection half
      offB[h][c] = o;
    }
  }

  int lane = tid & 63, wv = tid >> 6;
  int wm = (wv & 1) * 128;    // wave A-half
  int wn = (wv >> 1) * 64;    // wave B 64-col range
  int lrow = lane & 15, quad = lane >> 4;
  int cb = wn & 64;
  int sx0 = (quad ^ (lrow & 7)) * 8;
  int sx1 = ((quad + 4) ^ (lrow & 7)) * 8;
  const u16* Awb = &A[0][wm >> 7][0];
  const u16* Bwb = &B[0][wn >> 7][0];

  f4v acc[8][4];
#pragma unroll
  for (int i = 0; i < 8; i++)
#pragma unroll
    for (int j = 0; j < 4; j++) acc[i][j] = (f4v){0.f, 0.f, 0.f, 0.f};
  s8v a[4][2], b0[2][2], b1[2][2];

  // prologue: tile0 all 4 halves, tile1 B-lo + A-lo
  STAGE_A(0, 0, 0); STAGE_A(0, 1, 0); STAGE_B(0, 0, 0); STAGE_B(0, 1, 0);
  STAGE_B(1, 0, 1); STAGE_A(1, 0, 1);
  WAITV(4);
  BARRIER();

#pragma unroll 1
  for (int kt = 0; kt < 12; kt += 2) {
    KTILE(kt, 0, 12, 4);
    KTILE(kt + 1, 1, 12, 4);
  }

  long hb = (long)baserow[e] + (long)mt * 256;
#pragma unroll
  for (int mi = 0; mi < 8; mi++) {
#pragma unroll
    for (int r4 = 0; r4 < 4; r4++) {
      int m = wm + (mi >> 2) * 64 + (mi & 3) * 16 + quad * 4 + r4;
      if (mt * 256 + m < cnt) {
#pragma unroll
        for (int pr = 0; pr < 2; pr++) {
          float gv = acc[mi][pr * 2][r4], uv = acc[mi][pr * 2 + 1][r4];
          float h = gv / (1.f + __expf(-gv)) * uv;
          H[(hb + m) * FF + NT * 128 + (wn >> 1) + pr * 16 + lrow] = f2bf(h);
        }
      }
    }
  }
}

// ---------------- GEMM2: ybuf[(t,k)] = (H @ wo^T) * w ----------------
// BM=256 H rows, BN=256 DIM cols (nt in {0,1,2}), BK=64, NK=48
__global__ __launch_bounds__(512, 2) void gemm2_kernel(
    const u16* __restrict__ Hsrc, const u16* __restrict__ wob,
    float* __restrict__ ybuf, const int* __restrict__ counts, const int* __restrict__ baserow,
    const int* __restrict__ ltk, const float* __restrict__ lw) {
  int id = blockIdx.x;
  int wgi = (id & 7) * 30 + (id >> 3);
  int e = wgi / 30;
  int rem = wgi - e * 30;
  int mt = rem / 3;
  int nt = rem - mt * 3;
  int cnt = counts[e];
  if (mt * 256 >= cnt) return;

  __shared__ u16 A[2][2][128 * 64];
  __shared__ u16 B[2][2][128 * 64];
  __shared__ int stok[256];
  __shared__ float sw[256];
  int tid = threadIdx.x;
  if (tid < 256) {
    int r = mt * 256 + tid; if (r > cnt - 1) r = cnt - 1;
    stok[tid] = ltk[e * LSTR + r];
    sw[tid] = lw[e * LSTR + r];
  }
  __syncthreads();
  int hb0 = baserow[e];

  // ---- precompute staging offsets ----
  const u16* gAbase = Hsrc;
  const u16* gBbase = wob;
  u16* aLds = &A[0][0][0];
  u16* bLds = &B[0][0][0];
  int t8 = tid * 8;
  int row0 = tid >> 3, row1 = row0 + 64;
  int lsw = ((tid & 7) ^ (row0 & 7)) * 8;
  u32 offA[2][2], offB[2][2];
#pragma unroll
  for (int h = 0; h < 2; h++) {
#pragma unroll
    for (int c = 0; c < 2; c++) {
      int rowc = c ? row1 : row0;
      int r_ = mt * 256 + h * 128 + rowc; if (r_ > cnt - 1) r_ = cnt - 1;
      offA[h][c] = (u32)(hb0 + r_) * FF + lsw;
      offB[h][c] = (u32)(e * DIM + nt * 256 + h * 128 + rowc) * FF + lsw;
    }
  }

  int lane = tid & 63, wv = tid >> 6;
  int wm = (wv & 1) * 128;
  int wn = (wv >> 1) * 64;
  int lrow = lane & 15, quad = lane >> 4;
  int cb = wn & 64;
  int sx0 = (quad ^ (lrow & 7)) * 8;
  int sx1 = ((quad + 4) ^ (lrow & 7)) * 8;
  const u16* Awb = &A[0][wm >> 7][0];
  const u16* Bwb = &B[0][wn >> 7][0];

  f4v acc[8][4];
#pragma unroll
  for (int i = 0; i < 8; i++)
#pragma unroll
    for (int j = 0; j < 4; j++) acc[i][j] = (f4v){0.f, 0.f, 0.f, 0.f};
  s8v a[4][2], b0[2][2], b1[2][2];

  STAGE_A(0, 0, 0); STAGE_A(0, 1, 0); STAGE_B(0, 0, 0); STAGE_B(0, 1, 0);
  STAGE_B(1, 0, 1); STAGE_A(1, 0, 1);
  WAITV(4);
  BARRIER();

#pragma unroll 1
  for (int kt = 0; kt < 48; kt += 2) {
    KTILE(kt, 0, 48, 4);
    KTILE(kt + 1, 1, 48, 4);
  }

#pragma unroll
  for (int mi = 0; mi < 8; mi++) {
#pragma unroll
    for (int r4 = 0; r4 < 4; r4++) {
      int m = wm + (mi >> 2) * 64 + (mi & 3) * 16 + quad * 4 + r4;
      if (mt * 256 + m < cnt) {
        int entry = stok[m];
        float w = sw[m];
        long ob = (long)entry * DIM + nt * 256 + wn;
#pragma unroll
        for (int jc = 0; jc < 4; jc++)
          ybuf[ob + jc * 16 + lrow] = acc[mi][jc][r4] * w;
      }
    }
  }
}

// ---------------- combine: out[t] = sum of kept (t,k) contributions ----------------
__global__ __launch_bounds__(256) void combine_kernel(
    const float* __restrict__ ybuf, const int* __restrict__ kflags, float* __restrict__ out) {
  int idx = blockIdx.x * 256 + threadIdx.x;   // [0, T*DIM/4)
  int t = idx / (DIM / 4);
  int d4 = idx - t * (DIM / 4);
  int kf = kflags[t];
  float4 r = {0.f, 0.f, 0.f, 0.f};
  if (kf & 1) {
    float4 a = ((const float4*)(ybuf + (long)(2 * t) * DIM))[d4];
    r.x += a.x; r.y += a.y; r.z += a.z; r.w += a.w;
  }
  if (kf & 2) {
    float4 b = ((const float4*)(ybuf + (long)(2 * t + 1) * DIM))[d4];
    r.x += b.x; r.y += b.y; r.z += b.z; r.w += b.w;
  }
  ((float4*)out)[idx] = r;
}

// ---------------- aux loss ----------------
__global__ void aux_kernel(const int* __restrict__ fcnt, const float* __restrict__ psum,
                           const float* __restrict__ zsum, float* __restrict__ outaux) {
  if (threadIdx.x == 0 && blockIdx.x == 0) {
    float lb = 0.f;
    for (int e = 0; e < 8; e++)
      lb += ((float)fcnt[e] / (float)(T_TOK * 2)) * (psum[e] / (float)T_TOK);
    lb *= 8.f;
    float z = zsum[0] / (float)T_TOK;
    outaux[0] = 0.01f * lb + 0.001f * z;
  }
}

extern "C" void kernel_launch(void* const* d_in, const int* in_sizes, int n_in,
                              void* d_out, int out_size, void* d_ws, size_t ws_size,
                              hipStream_t stream) {
  const float* x = (const float*)d_in[0];
  const float* wgate = (const float*)d_in[1];
  const float* wig = (const float*)d_in[2];
  const float* wiu = (const float*)d_in[3];
  const float* wo = (const float*)d_in[4];
  float* out = (float*)d_out;

  char* ws = (char*)d_ws;
  size_t off = 0;
  auto alloc = [&](size_t bytes) {
    void* p = ws + off;
    off += (bytes + 255) & ~(size_t)255;
    return p;
  };
  int* ctrl = (int*)alloc(256);
  u16* xb = (u16*)alloc((size_t)T_TOK * DIM * 2);
  u16* wgb = (u16*)alloc((size_t)NE * FF * DIM * 2);
  u16* wub = (u16*)alloc((size_t)NE * FF * DIM * 2);   // MUST stay contiguous after wgb
  u16* wob = (u16*)alloc((size_t)NE * DIM * FF * 2);
  u16* Hbuf = (u16*)alloc((size_t)(T_TOK * 2 + 256) * FF * 2);
  int* tki = (int*)alloc((size_t)T_TOK * 2 * 4);
  float* tkp = (float*)alloc((size_t)T_TOK * 2 * 4);
  int* ltk = (int*)alloc((size_t)NE * LSTR * 4);
  float* lw = (float*)alloc((size_t)NE * LSTR * 4);
  float* probs = (float*)alloc((size_t)T_TOK * 8 * 4);
  float* lse2 = (float*)alloc((size_t)T_TOK * 4);
  int* kflags = (int*)alloc((size_t)T_TOK * 4);
  // ybuf [T*2, DIM] fp32 (50.3MB) aliases wgb+wub (75.5MB): weights dead after gemm1
  float* ybuf = (float*)wgb;

  int* fcnt = ctrl;
  int* counts = ctrl + 8;
  int* baserow = ctrl + 16;
  float* psum = (float*)(ctrl + 24);
  float* zsum = (float*)(ctrl + 32);

  const int n8each = NE * FF * DIM / 8;
  hipMemsetAsync(ctrl, 0, 256, stream);
  cast3_kernel<<<3 * n8each / 256, 256, 0, stream>>>(wig, wiu, wo, wgb, wub, wob, n8each);
  router_kernel<<<T_TOK / 4, 256, 0, stream>>>(x, wgate, xb, tki, tkp, probs, lse2);
  reduce_router_kernel<<<T_TOK / 1024, 1024, 0, stream>>>(tki, probs, lse2, fcnt, psum, zsum);
  rank_dispatch_kernel<<<1, 1024, 0, stream>>>(tki, tkp, ltk, lw, counts, baserow, kflags);
  gemm1_kernel<<<1920, 512, 0, stream>>>(xb, wgb, wub, Hbuf, counts, baserow, ltk);
  gemm2_kernel<<<240, 512, 0, stream>>>(Hbuf, wob, ybuf, counts, baserow, ltk, lw);
  combine_kernel<<<T_TOK * DIM / 4 / 256, 256, 0, stream>>>(ybuf, kflags, out);
  aux_kernel<<<1, 64, 0, stream>>>(fcnt, psum, zsum, out + (size_t)T_TOK * DIM);
}